// Round 5
// baseline (1087.978 us; speedup 1.0000x reference)
//
#include <hip/hip_runtime.h>
#include <hip/hip_bf16.h>
#include <math.h>

// Problem constants: T=2048, B=4096, IN_S=1, H=20, OUT_S=1
#define TT 2048
#define BB 4096
#define HH 20

typedef float v2f __attribute__((ext_vector_type(2)));

#define L2E 1.4426950408889634f  // log2(e)

__device__ __forceinline__ float rcp_fast(float x)  { return __builtin_amdgcn_rcpf(x); }
__device__ __forceinline__ float exp2_fast(float x) { return __builtin_amdgcn_exp2f(x); }

// Backend selects v_pk_fma_f32 — no inline-asm pinning of the FMA (R5 lesson).
__device__ __forceinline__ v2f pk_fma(v2f a, v2f b, v2f c) {
    return __builtin_elementwise_fma(a, b, c);
}

// One wave per block, TWO batches per wave (lanes [0..19],[20..39]); lanes
// 40/41 carry the W_out dot (y-offload, R9).
// R13 change vs the 804us kernel: NO LDS AT ALL. The h broadcast (20-lane
// all-gather) goes through ds_bpermute_b32 register-to-register instead of
// ds_write -> visibility wait -> lgkmcnt -> ds_read (~200-250cy round trip
// on the serial chain). Each lane keeps its own h_j in a register; 20
// bpermutes with precomputed byte addresses (bg*20+k)*4 gather the group's
// h. The bpermutes pipeline (compiler watermarks lgkmcnt), so the first
// FMA pair starts as soon as its pair lands — vs the all-or-nothing
// read-after-write before. Idle lanes 42-63 stay active, fetch garbage
// from lanes 40-59 into dead accumulators — harmless.
// R12 post-mortem: weight-remat theory DEAD (pins didn't move VGPR_Count=68;
// weights live on the AGPR side of the unified file — counter shows arch
// VGPRs only). FETCH/WRITE=4x ideal is cacheline amplification of the 8B
// strided u/y pattern, not spills; HBM at 3.9% is irrelevant.
// Model (R10): wall = T x C(per-wave step); all 2048 chains run concurrently,
// so ONLY the per-step serial chain C matters. C ~= all-gather + dot +
// 4-deep trans chain. This attacks the all-gather leg.
__global__ __launch_bounds__(64, 2) void lstm_fused_kernel(
    const float* __restrict__ u,      // [T, B, 1]
    const float* __restrict__ W_ih,   // [4H, 1]
    const float* __restrict__ W_hh,   // [4H, H]
    const float* __restrict__ W_out,  // [1, H]
    float* __restrict__ y)            // [T, B, 1]
{
    const int lane  = threadIdx.x;
    const int group = lane / HH;          // 0..3 (2,3 == y/idle)
    const int j     = lane - group * HH;  // 0..19
    const bool is_y = (lane >= 2 * HH) && (lane < 2 * HH + 2);  // lanes 40,41
    const int b_real = blockIdx.x * 2 + group;
    const bool active = (group < 2) && (b_real < BB);
    const int b = active ? b_real : 0;

    // ---- Weights in registers, packed along k: wg[g][m] = (w[2m], w[2m+1]).
    // Pre-scaled into exp2 domain: i,f,o rows * -log2(e); g row * -2*log2(e).
    v2f wg[4][HH / 2];
    const float gsc[4] = {-L2E, -L2E, -2.0f * L2E, -L2E};
    #pragma unroll
    for (int g = 0; g < 4; ++g) {
        #pragma unroll
        for (int m = 0; m < HH / 2; ++m) {
            wg[g][m].x = gsc[g] * W_hh[(g * HH + j) * HH + 2 * m];
            wg[g][m].y = gsc[g] * W_hh[(g * HH + j) * HH + 2 * m + 1];
        }
    }
    v2f wih2[4];
    #pragma unroll
    for (int g = 0; g < 4; ++g) { wih2[g].x = gsc[g] * W_ih[g * HH + j]; wih2[g].y = 0.0f; }

    // y-offload wiring: broadcast-source group per lane, W_out row for y-lanes.
    int bg = group;
    if (lane >= 2 * HH) {
        bg = is_y ? (lane - 2 * HH) : 2;  // lane40->group0's h, lane41->group1's
        if (is_y) {
            #pragma unroll
            for (int m = 0; m < HH / 2; ++m) {
                wg[0][m].x = W_out[2 * m];      // UNSCALED: a0 = dot(W_out, h)
                wg[0][m].y = W_out[2 * m + 1];
            }
            wih2[0].x = 0.0f;  // y has no u-term
        }
    }

    // ---- PIN: identity asm (scalar operands) keeps the final weight values
    // as opaque defs (kept from R12; harmless, avoids re-derivation).
    #pragma unroll
    for (int g = 0; g < 4; ++g) {
        #pragma unroll
        for (int m = 0; m < HH / 2; ++m) {
            asm volatile("" : "+v"(wg[g][m].x), "+v"(wg[g][m].y));
        }
        asm volatile("" : "+v"(wih2[g].x));
    }

    // ---- bpermute byte-addresses: lane fetches h of lanes bg*20+k.
    int bpa[HH];
    #pragma unroll
    for (int k = 0; k < HH; ++k) bpa[k] = (bg * HH + k) * 4;

    float c = 0.0f;
    int hbits = 0;  // own h_{t-1} as bits; h_{-1} = 0
    const float* __restrict__ up = u + b;
    float* yp = y + blockIdx.x * 2 + (lane - 2 * HH);  // valid only on y-lanes

    float u_cur[8];
    #pragma unroll
    for (int k = 0; k < 8; ++k) u_cur[k] = up[(size_t)k * BB];

    for (int t8 = 0; t8 < TT; t8 += 8) {
        const int tn = (t8 + 8 < TT) ? (t8 + 8) : t8;
        float u_nxt[8];
        #pragma unroll
        for (int k = 0; k < 8; ++k) u_nxt[k] = up[(size_t)(tn + k) * BB];

        float y8[8];  // on y-lanes: y8[tt] = y_{t8+tt-1} (gather sees h one step back)

        #pragma unroll
        for (int tt = 0; tt < 8; ++tt) {
            // ---- all-gather h_{t-1}: 20 ds_bpermute (register crossbar, no
            // LDS storage, no write->read round trip) ----
            v2f h2[10];
            #pragma unroll
            for (int m = 0; m < 10; ++m) {
                const int lo = __builtin_amdgcn_ds_bpermute(bpa[2 * m],     hbits);
                const int hi = __builtin_amdgcn_ds_bpermute(bpa[2 * m + 1], hbits);
                h2[m].x = __int_as_float(lo);
                h2[m].y = __int_as_float(hi);
            }

            const float uv = u_cur[tt];
            const v2f uv2 = {uv, uv};
            v2f a0 = wih2[0] * uv2;   // v_pk_mul_f32; .y term is 0
            v2f a1 = wih2[1] * uv2;
            v2f a2 = wih2[2] * uv2;
            v2f a3 = wih2[3] * uv2;

            // 40 v_pk_fma_f32; 4 accumulators round-robin -> dep spacing
            // 4 insts (8 cyc) > 4-cyc FMA latency. o-gate (a3) last: its
            // result is needed ~40cy later than the others.
            #pragma unroll
            for (int m = 0; m < 10; ++m) {
                v2f hp = h2[m];
                a2 = pk_fma(wg[2][m], hp, a2);
                a1 = pk_fma(wg[1][m], hp, a1);
                a0 = pk_fma(wg[0][m], hp, a0);
                a3 = pk_fma(wg[3][m], hp, a3);
            }
            const float g2 = a2.x + a2.y;  // exp2-domain pre-acts
            const float g1 = a1.x + a1.y;
            const float g0 = a0.x + a0.y;  // (y-lanes: y value)
            const float g3 = a3.x + a3.y;
            y8[tt] = g0;                   // only consumed on y-lanes

            // ---- activations: 5 exp2, 2 rcp (merged denominators) ----
            const float eg = exp2_fast(g2);   // e^{-2 x_g}  (sign-safe: |x_g|<~6)
            const float ef = exp2_fast(g1);   // e^{-x_f}
            const float ei = exp2_fast(g0);   // e^{-x_i}
            const float eo = exp2_fast(g3);   // e^{-x_o}
            const float pg  = 1.0f + eg;
            const float pf  = 1.0f + ef;
            const float pi_ = 1.0f + ei;
            const float po  = 1.0f + eo;
            const float mg  = 1.0f - eg;      // sign of tanh(x_g) falls out naturally

            // c' = f*c + i*tanh(g), one rcp. c itself retires OFF the h-path:
            // tanh(c') needs only |num| (|c'| = |num|*r, r>0) and sign(num).
            const float m1  = pg * pi_;
            const float num = fmaf(c, m1, mg * pf);
            const float r   = rcp_fast(pf * m1);
            c = num * r;                               // for next step only
            const float kn  = (-2.0f * L2E) * fabsf(num);  // overlaps the rcp
            const float ec  = exp2_fast(kn * r);       // e^{-2|c|} <= 1, no overflow
            const float pc  = 1.0f + ec;
            const float mcs = copysignf(1.0f - ec, num);   // sign(c)==sign(num)
            const float h   = mcs * rcp_fast(po * pc);

            // ---- publish h_t: just update own register (bpermute source) ----
            hbits = __float_as_int(h);
        }

        if (is_y) {
            #pragma unroll
            for (int k = 0; k < 8; ++k) {
                const int idx = t8 - 1 + k;
                if (idx >= 0) yp[(size_t)idx * BB] = y8[k];
            }
        }

        #pragma unroll
        for (int k = 0; k < 8; ++k) u_cur[k] = u_nxt[k];
    }

    // Epilogue: y_{T-1} from the final h (one more gather, y-lanes only).
    {
        v2f ay = {0.0f, 0.0f};
        #pragma unroll
        for (int m = 0; m < 10; ++m) {
            const int lo = __builtin_amdgcn_ds_bpermute(bpa[2 * m],     hbits);
            const int hi = __builtin_amdgcn_ds_bpermute(bpa[2 * m + 1], hbits);
            v2f hp; hp.x = __int_as_float(lo); hp.y = __int_as_float(hi);
            ay = pk_fma(wg[0][m], hp, ay);
        }
        if (is_y) yp[(size_t)(TT - 1) * BB] = ay.x + ay.y;
    }
}

extern "C" void kernel_launch(void* const* d_in, const int* in_sizes, int n_in,
                              void* d_out, int out_size, void* d_ws, size_t ws_size,
                              hipStream_t stream) {
    const float* u     = (const float*)d_in[0];   // [2048, 4096, 1]
    const float* W_ih  = (const float*)d_in[1];   // [80, 1]
    const float* W_hh  = (const float*)d_in[2];   // [80, 20]
    const float* W_out = (const float*)d_in[3];   // [1, 20]
    float* y = (float*)d_out;                      // [2048, 4096, 1]

    const int blocks = BB / 2;  // 2 batches per single-wave block -> 2048 = 2 waves/SIMD
    lstm_fused_kernel<<<dim3(blocks), dim3(64), 0, stream>>>(u, W_ih, W_hh, W_out, y);
}

// Round 6
// 752.148 us; speedup vs baseline: 1.4465x; 1.4465x over previous
//
#include <hip/hip_runtime.h>
#include <hip/hip_bf16.h>
#include <math.h>

// Problem constants: T=2048, B=4096, IN_S=1, H=20, OUT_S=1
#define TT 2048
#define BB 4096
#define HH 20

typedef float v2f __attribute__((ext_vector_type(2)));

#define L2E 1.4426950408889634f  // log2(e)

__device__ __forceinline__ float rcp_fast(float x)  { return __builtin_amdgcn_rcpf(x); }
__device__ __forceinline__ float exp2_fast(float x) { return __builtin_amdgcn_exp2f(x); }

__device__ __forceinline__ v2f pk_fma(v2f a, v2f b, v2f c) {
    return __builtin_elementwise_fma(a, b, c);
}
__device__ __forceinline__ v2f exp2v(v2f x) { v2f r; r.x = exp2_fast(x.x); r.y = exp2_fast(x.y); return r; }
__device__ __forceinline__ v2f rcpv(v2f x)  { v2f r; r.x = rcp_fast(x.x);  r.y = rcp_fast(x.y);  return r; }
__device__ __forceinline__ v2f absv(v2f x)  { v2f r; r.x = fabsf(x.x);     r.y = fabsf(x.y);     return r; }
__device__ __forceinline__ v2f csignv(v2f x, v2f s) {
    v2f r; r.x = copysignf(x.x, s.x); r.y = copysignf(x.y, s.y); return r;
}

// R14: FOUR batches per wave, 2 hidden units per lane.
//   lanes 0..39 : q = lane/10 (batch-in-block), p = lane%10, owns j = 2p, 2p+1
//   lanes 40..43: y-lanes, one per batch (W_out dot via accumulator alias)
//   lanes 44..63: idle (duplicate batch-0 work into scratch, harmless)
// Why: R13 showed the DS pipe's per-op cost dominates (20 bpermutes = +290cy;
// wide b128 gather is the right primitive), so no single chain leg is big
// enough to attack. Instead AMORTIZE the whole per-step serial chain (gather
// RT + dot + trans chain) over 4 batches in ONE instruction stream: same 6 DS
// ops per step (1 ds_write_b64 + 5 ds_read_b128 per lane), 80 pk_fma (vs 40),
// v2f activations (two independent j-chains per lane = ILP inside trans
// latency). BB/4 = 1024 blocks = EXACTLY 1 wave/SIMD: zero cross-wave DS and
// issue interference (2-wave overlap was measurably poor: 1.33->2.0 waves
// gave only 984->967 in the R8 ladder).
// R13 post-mortem: bpermute all-gather DEAD (+20cy per DS op on the chain).
// R12 post-mortem: weight-remat theory DEAD (pins didn't move VGPR=68).
// Model: wall = T x C(chain); C paid once per 4 batches here vs per 2 before.
__global__ __launch_bounds__(64, 1) void lstm_fused_kernel(
    const float* __restrict__ u,      // [T, B, 1]
    const float* __restrict__ W_ih,   // [4H, 1]
    const float* __restrict__ W_hh,   // [4H, H]
    const float* __restrict__ W_out,  // [1, H]
    float* __restrict__ y)            // [T, B, 1]
{
    // hbuf[0..79]  = h for 4 batches x 20 units
    // hbuf[80..127] = scratch for y/idle lane writes (keeps the stream uniform)
    __shared__ __align__(16) float hbuf[128];

    const int lane = threadIdx.x;
    int q, wa, jbase;
    bool is_y = false;
    if (lane < 40) {
        q = lane / 10;
        const int p = lane - q * 10;
        wa = q * HH + 2 * p;          // write offset (floats), 8B-aligned
        jbase = 2 * p;
    } else {
        is_y = (lane < 44);
        q = is_y ? (lane - 40) : 0;   // y-lane reads its batch's h
        wa = 4 * HH + (lane - 40) * 2; // scratch area
        jbase = 0;
    }

    // h_{-1} = 0 everywhere.
    for (int i = lane; i < 128; i += 64) hbuf[i] = 0.0f;
    asm volatile("" ::: "memory");  // one-time, outside the hot loop

    // ---- Weights: per lane, rows (g, jbase) and (g, jbase+1), k-packed.
    // Pre-scaled into exp2 domain: i,f,o rows * -log2(e); g row * -2*log2(e).
    v2f wgv[4][2][10];
    v2f wihv[4][2];
    const float gsc[4] = {-L2E, -L2E, -2.0f * L2E, -L2E};
    #pragma unroll
    for (int g = 0; g < 4; ++g) {
        #pragma unroll
        for (int r = 0; r < 2; ++r) {
            const int row = g * HH + jbase + r;
            #pragma unroll
            for (int m = 0; m < 10; ++m) {
                wgv[g][r][m].x = gsc[g] * W_hh[row * HH + 2 * m];
                wgv[g][r][m].y = gsc[g] * W_hh[row * HH + 2 * m + 1];
            }
            wihv[g][r].x = gsc[g] * W_ih[row];
            wihv[g][r].y = 0.0f;
        }
    }
    if (lane >= 40) {  // y-lanes (idles too, harmless): gate0/r0 row := W_out
        #pragma unroll
        for (int m = 0; m < 10; ++m) {
            wgv[0][0][m].x = W_out[2 * m];      // UNSCALED: a[0][0] = dot(W_out, h)
            wgv[0][0][m].y = W_out[2 * m + 1];
        }
        wihv[0][0].x = 0.0f;                    // y has no u-term
    }

    // Keep final weight values as opaque defs (cheap insurance vs remat).
    #pragma unroll
    for (int g = 0; g < 4; ++g) {
        #pragma unroll
        for (int r = 0; r < 2; ++r) {
            #pragma unroll
            for (int m = 0; m < 10; ++m)
                asm volatile("" : "+v"(wgv[g][r][m].x), "+v"(wgv[g][r][m].y));
            asm volatile("" : "+v"(wihv[g][r].x));
        }
    }

    const v2f* hs = (const v2f*)&hbuf[q * HH];  // 16B-aligned (q*80 bytes)
    v2f* hw = (v2f*)&hbuf[wa];                  // no restrict: must alias hs

    v2f cv = {0.0f, 0.0f};
    const float* __restrict__ up = u + (size_t)blockIdx.x * 4 + q;
    float* yp = y + (size_t)blockIdx.x * 4 + (lane - 40);  // valid on y-lanes

    float u_cur[8];
    #pragma unroll
    for (int k = 0; k < 8; ++k) u_cur[k] = up[(size_t)k * BB];

    const v2f one = {1.0f, 1.0f};
    const v2f n2l2e = {-2.0f * L2E, -2.0f * L2E};

    for (int t8 = 0; t8 < TT; t8 += 8) {
        const int tn = (t8 + 8 < TT) ? (t8 + 8) : t8;
        float u_nxt[8];
        #pragma unroll
        for (int k = 0; k < 8; ++k) u_nxt[k] = up[(size_t)(tn + k) * BB];

        float y8[8];  // y-lanes: y8[tt] = y_{t8+tt-1} (gather sees h one step back)

        #pragma unroll
        for (int tt = 0; tt < 8; ++tt) {
            // ---- gather own batch's h_{t-1}: 5 x ds_read_b128 ----
            v2f h2[10];
            #pragma unroll
            for (int m = 0; m < 10; ++m) h2[m] = hs[m];

            const float uv = u_cur[tt];
            const v2f uv2 = {uv, uv};
            v2f a[4][2];
            #pragma unroll
            for (int g = 0; g < 4; ++g) {
                #pragma unroll
                for (int r = 0; r < 2; ++r) a[g][r] = wihv[g][r] * uv2;
            }

            // 80 v_pk_fma_f32; 8 accumulators round-robin -> 16cy dep spacing.
            #pragma unroll
            for (int m = 0; m < 10; ++m) {
                const v2f hp = h2[m];
                a[2][0] = pk_fma(wgv[2][0][m], hp, a[2][0]);
                a[2][1] = pk_fma(wgv[2][1][m], hp, a[2][1]);
                a[1][0] = pk_fma(wgv[1][0][m], hp, a[1][0]);
                a[1][1] = pk_fma(wgv[1][1][m], hp, a[1][1]);
                a[0][0] = pk_fma(wgv[0][0][m], hp, a[0][0]);
                a[0][1] = pk_fma(wgv[0][1][m], hp, a[0][1]);
                a[3][0] = pk_fma(wgv[3][0][m], hp, a[3][0]);
                a[3][1] = pk_fma(wgv[3][1][m], hp, a[3][1]);
            }
            // preacts packed (j0, j1) per gate
            v2f gi, gf, gg, go;
            gi.x = a[0][0].x + a[0][0].y;  gi.y = a[0][1].x + a[0][1].y;
            gf.x = a[1][0].x + a[1][0].y;  gf.y = a[1][1].x + a[1][1].y;
            gg.x = a[2][0].x + a[2][0].y;  gg.y = a[2][1].x + a[2][1].y;
            go.x = a[3][0].x + a[3][0].y;  go.y = a[3][1].x + a[3][1].y;
            y8[tt] = gi.x;  // y-lanes: their a[0][0] is the W_out dot

            // ---- activations, v2f (two independent j-chains interleave):
            // 10 exp2 + 4 rcp per lane, merged denominators (R9/R10 algebra).
            const v2f eg = exp2v(gg);   // e^{-2 x_g}
            const v2f ef = exp2v(gf);   // e^{-x_f}
            const v2f ei = exp2v(gi);   // e^{-x_i}
            const v2f eo = exp2v(go);   // e^{-x_o}
            const v2f pg = one + eg, pf = one + ef, pi2 = one + ei, po = one + eo;
            const v2f mg = one - eg;    // tanh(x_g) sign falls out naturally

            const v2f m1  = pg * pi2;
            const v2f num = pk_fma(cv, m1, mg * pf);
            const v2f rv  = rcpv(pf * m1);
            cv = num * rv;                                // next step only
            const v2f kn  = absv(num) * n2l2e;            // overlaps the rcp
            const v2f ec  = exp2v(kn * rv);               // e^{-2|c|} <= 1
            const v2f pc  = one + ec;
            const v2f mcs = csignv(one - ec, num);        // sign(c)==sign(num)
            const v2f hv  = mcs * rcpv(po * pc);

            // ---- publish h_t: one ds_write_b64 (compiler orders vs gather) ----
            *hw = hv;
        }

        if (is_y) {
            #pragma unroll
            for (int k = 0; k < 8; ++k) {
                const int idx = t8 - 1 + k;
                if (idx >= 0) yp[(size_t)idx * BB] = y8[k];
            }
        }

        #pragma unroll
        for (int k = 0; k < 8; ++k) u_cur[k] = u_nxt[k];
    }

    // Epilogue: y_{T-1} from the final h (y-lanes only).
    {
        v2f ay = {0.0f, 0.0f};
        #pragma unroll
        for (int m = 0; m < 10; ++m) ay = pk_fma(wgv[0][0][m], hs[m], ay);
        if (is_y) yp[(size_t)(TT - 1) * BB] = ay.x + ay.y;
    }
}

extern "C" void kernel_launch(void* const* d_in, const int* in_sizes, int n_in,
                              void* d_out, int out_size, void* d_ws, size_t ws_size,
                              hipStream_t stream) {
    const float* u     = (const float*)d_in[0];   // [2048, 4096, 1]
    const float* W_ih  = (const float*)d_in[1];   // [80, 1]
    const float* W_hh  = (const float*)d_in[2];   // [80, 20]
    const float* W_out = (const float*)d_in[3];   // [1, 20]
    float* y = (float*)d_out;                      // [2048, 4096, 1]

    const int blocks = BB / 4;  // 4 batches per single-wave block -> 1024 = 1 wave/SIMD
    lstm_fused_kernel<<<dim3(blocks), dim3(64), 0, stream>>>(u, W_ih, W_hh, W_out, y);
}